// Round 16
// baseline (2367.671 us; speedup 1.0000x reference)
//
#include <hip/hip_runtime.h>

typedef unsigned short u16;
typedef __attribute__((ext_vector_type(4))) float f32x4;
typedef __attribute__((ext_vector_type(8))) short s16x8;
typedef __attribute__((ext_vector_type(4))) short s16x4;

static constexpr int V = 32000;
static constexpr int C = 1024;
static constexpr int T = 1024;
static constexpr int H = 16;
static constexpr int L = 8;
static constexpr int B = 4;
static constexpr int HS = 64;
static constexpr int BT = B * T;   // 4096
static constexpr int C4 = 4 * C;   // 4096
static constexpr int C3 = 3 * C;   // 3072

__device__ __forceinline__ u16 f2bf(float f) {
  union { float f; unsigned u; } v; v.f = f;
  unsigned r = v.u + 0x7fffu + ((v.u >> 16) & 1u);
  return (u16)(r >> 16);
}

__device__ __forceinline__ void gload16(const u16* g, u16* l) {
  __builtin_amdgcn_global_load_lds(
      (const __attribute__((address_space(1))) void*)g,
      (__attribute__((address_space(3))) void*)l, 16, 0, 0);
}

// ---------- block reduction (256 threads) ----------
__device__ __forceinline__ float blockReduceSum(float v) {
  __shared__ float red[4];
  int lane = threadIdx.x & 63, w = threadIdx.x >> 6;
#pragma unroll
  for (int m = 32; m >= 1; m >>= 1) v += __shfl_xor(v, m, 64);
  if (lane == 0) red[w] = v;
  __syncthreads();
  float r = red[0] + red[1] + red[2] + red[3];
  __syncthreads();
  return r;
}

// ---------- embed (vectorized: one float4 per thread) ----------
__global__ __launch_bounds__(256) void k_embed(
    const int* __restrict__ idx, const float* __restrict__ tok,
    const float* __restrict__ pos, float* __restrict__ x, u16* __restrict__ xb) {
  int bt = blockIdx.x;
  int t = bt & (T - 1);
  int row = idx[bt];
  int tid = threadIdx.x;
  f32x4 tv = ((const f32x4*)(tok + (size_t)row * C))[tid];
  f32x4 pv = ((const f32x4*)(pos + (size_t)t * C))[tid];
  f32x4 y;
  s16x4 yb;
#pragma unroll
  for (int j = 0; j < 4; ++j) {
    y[j] = tv[j] + pv[j];
    yb[j] = (short)f2bf(y[j]);
  }
  ((f32x4*)(x + (size_t)bt * C))[tid] = y;
  ((s16x4*)(xb + (size_t)bt * C))[tid] = yb;
}

// ---------- weight convert+transpose: fp32 [K,N] -> bf16 [N,K] ----------
__global__ __launch_bounds__(256) void k_transpose(
    const float* __restrict__ W, u16* __restrict__ Wt, int K, int N,
    size_t sW, size_t sWt) {
  __shared__ float tile[64][65];
  const float* Wz = W + sW * blockIdx.z;
  u16* Wtz = Wt + sWt * blockIdx.z;
  int n0 = blockIdx.x * 64, k0 = blockIdx.y * 64;
  int tc = threadIdx.x & 63, tr = threadIdx.x >> 6;
#pragma unroll
  for (int i = 0; i < 16; ++i) {
    int r = tr + i * 4;
    tile[r][tc] = Wz[(size_t)(k0 + r) * N + (n0 + tc)];
  }
  __syncthreads();
#pragma unroll
  for (int i = 0; i < 16; ++i) {
    int r = tr + i * 4;  // n-offset within tile
    Wtz[(size_t)(n0 + r) * K + (k0 + tc)] = f2bf(tile[tc][r]);
  }
}

// ---------- GEMM 128x128, 3-stage ring + T2 swizzle ----------
// VT=1 (QKV): blocks with nb>=2C write V projection transposed into Vtp.
template <int OUT_BF16, int RELU, int HAS_BIAS, int HAS_RES, int VT>
__global__ __launch_bounds__(256, 2) void k_gemm(
    const u16* __restrict__ A, const u16* __restrict__ Bt,
    const float* __restrict__ bias, const float* __restrict__ Res,
    float* __restrict__ Cf, u16* __restrict__ Cb, u16* __restrict__ Vtp,
    int M, int N, int K) {
  __shared__ u16 As[3][4096];
  __shared__ u16 Bs[3][4096];
  int tid = threadIdx.x;
  int lane = tid & 63, wid = tid >> 6;
  int lm = lane & 15, lg = lane >> 4;
  int wm = wid >> 1, wn = wid & 1;

  unsigned nbx = gridDim.x;
  unsigned nwg = nbx * gridDim.y;
  unsigned orig = blockIdx.y * nbx + blockIdx.x;
  unsigned f = ((nwg & 7u) == 0u) ? (orig & 7u) * (nwg >> 3) + (orig >> 3) : orig;
  int mb = (int)(f / nbx) * 128, nb = (int)(f % nbx) * 128;

  f32x4 acc[4][4];
#pragma unroll
  for (int i = 0; i < 4; ++i)
#pragma unroll
    for (int j = 0; j < 4; ++j) acc[i][j] = f32x4{0.f, 0.f, 0.f, 0.f};

  int row = tid >> 2, psl = tid & 3;
  int sl = psl ^ (((row & 15) >> 1) & 3);
  const u16* a0 = A + (size_t)(mb + row) * K + sl * 8;
  const u16* a1 = A + (size_t)(mb + 64 + row) * K + sl * 8;
  const u16* b0 = Bt + (size_t)(nb + row) * K + sl * 8;
  const u16* b1 = Bt + (size_t)(nb + 64 + row) * K + sl * 8;
  const int ld0 = wid * 512, ld1 = 2048 + wid * 512;
  const int lo = lm * 32 + ((lg ^ ((lm >> 1) & 3)) << 3);

  auto stage = [&](int t, int s) {
    int ko = t * 32;
    gload16(a0 + ko, &As[s][ld0]);
    gload16(a1 + ko, &As[s][ld1]);
    gload16(b0 + ko, &Bs[s][ld0]);
    gload16(b1 + ko, &Bs[s][ld1]);
  };

  int nK = K >> 5;
  stage(0, 0);
  stage(1, 1);
  for (int t = 0; t < nK; ++t) {
    int s = t % 3;
    if (t + 1 < nK)
      asm volatile("s_waitcnt vmcnt(4)" ::: "memory");
    else
      asm volatile("s_waitcnt vmcnt(0)" ::: "memory");
    __builtin_amdgcn_s_barrier();
    s16x8 af[4], bfr[4];
#pragma unroll
    for (int m = 0; m < 4; ++m)
      af[m] = *(const s16x8*)&As[s][(wm * 4 + m) * 512 + lo];
#pragma unroll
    for (int n = 0; n < 4; ++n)
      bfr[n] = *(const s16x8*)&Bs[s][(wn * 4 + n) * 512 + lo];
    if (t + 2 < nK) stage(t + 2, (t + 2) % 3);
    __builtin_amdgcn_s_setprio(1);
#pragma unroll
    for (int m = 0; m < 4; ++m)
#pragma unroll
      for (int n = 0; n < 4; ++n)
        acc[m][n] = __builtin_amdgcn_mfma_f32_16x16x32_bf16(af[m], bfr[n],
                                                            acc[m][n], 0, 0, 0);
    __builtin_amdgcn_s_setprio(0);
  }
  if (VT && nb >= 2 * C) {
    // V projection: write transposed [d][t] per (b,h); wave's 64 cols = 1 head
    int hh = ((nb + wn * 64) - 2 * C) >> 6;
#pragma unroll
    for (int m = 0; m < 4; ++m) {
      int t0 = mb + wm * 64 + m * 16 + lg * 4;
      int bb = t0 >> 10, tt = t0 & (T - 1);
      size_t vbase = ((size_t)(bb * H + hh) * HS) * T + tt;
#pragma unroll
      for (int n = 0; n < 4; ++n) {
        int d = n * 16 + lm;
        s16x4 pk;
#pragma unroll
        for (int r = 0; r < 4; ++r) pk[r] = (short)f2bf(acc[m][n][r]);
        *(s16x4*)&Vtp[vbase + (size_t)d * T] = pk;
      }
    }
    return;
  }
#pragma unroll
  for (int m = 0; m < 4; ++m) {
#pragma unroll
    for (int n = 0; n < 4; ++n) {
      int col = nb + wn * 64 + n * 16 + lm;
      float bv = HAS_BIAS ? bias[col] : 0.0f;
#pragma unroll
      for (int r = 0; r < 4; ++r) {
        int rw = mb + wm * 64 + m * 16 + lg * 4 + r;
        float v = acc[m][n][r] + bv;
        if (HAS_RES) v += Res[(size_t)rw * N + col];
        if (RELU) v = v > 0.f ? v : 0.f;
        if (OUT_BF16)
          Cb[(size_t)rw * N + col] = f2bf(v);
        else
          Cf[(size_t)rw * N + col] = v;
      }
    }
  }
}

// ---------- GEMM 256x256 8-phase (T2+T3+T4+T5) for w1 ----------
template <int OUT_BF16, int RELU, int HAS_BIAS, int HAS_RES>
__global__ __launch_bounds__(512) void k_gemm256(
    const u16* __restrict__ A, const u16* __restrict__ Bt,
    const float* __restrict__ bias, const float* __restrict__ Res,
    float* __restrict__ Cf, u16* __restrict__ Cb, int M, int N, int K) {
  __shared__ u16 As[2][16384];
  __shared__ u16 Bs[2][16384];
  const int tid = threadIdx.x;
  const int lane = tid & 63, wid = tid >> 6;
  const int lm = lane & 15, lg = lane >> 4;
  const int wr = wid >> 2, wc = wid & 3;

  unsigned nbx = gridDim.x;
  unsigned nwg = nbx * gridDim.y;
  unsigned orig = blockIdx.y * nbx + blockIdx.x;
  unsigned f =
      ((nwg & 7u) == 0u) ? (orig & 7u) * (nwg >> 3) + (orig >> 3) : orig;
  const int mb = (int)(f / nbx) * 256;
  const int nb = (int)(f % nbx) * 256;

  int aoff[4], boff[4], ldso[4];
#pragma unroll
  for (int h = 0; h < 4; ++h) {
    const int kk = h >> 1, p = h & 1;
    int rem = p * 512 + tid;
    int rblk = rem >> 6;
    int rem2 = rem & 63;
    int row16 = rem2 >> 2, psl = rem2 & 3;
    int sl = psl ^ ((row16 >> 1) & 3);
    int grow = rblk * 16 + row16;
    int gk = kk * 32 + sl * 8;
    aoff[h] = (mb + grow) * K + gk;
    boff[h] = (nb + grow) * K + gk;
    ldso[h] = kk * 8192 + p * 4096 + wid * 512;
  }
  const int lo = lm * 32 + ((lg ^ ((lm >> 1) & 3)) << 3);

  f32x4 acc[8][4];
#pragma unroll
  for (int i = 0; i < 8; ++i)
#pragma unroll
    for (int j = 0; j < 4; ++j) acc[i][j] = f32x4{0.f, 0.f, 0.f, 0.f};

  const int nK = K >> 6;
  gload16(A + aoff[0], &As[0][ldso[0]]);
  gload16(A + aoff[1], &As[0][ldso[1]]);
  gload16(Bt + boff[0], &Bs[0][ldso[0]]);
  gload16(Bt + boff[1], &Bs[0][ldso[1]]);
  gload16(A + aoff[2], &As[0][ldso[2]]);
  gload16(A + aoff[3], &As[0][ldso[3]]);
  gload16(Bt + boff[2], &Bs[0][ldso[2]]);
  gload16(Bt + boff[3], &Bs[0][ldso[3]]);
  asm volatile("s_waitcnt vmcnt(4)" ::: "memory");
  __builtin_amdgcn_s_barrier();

  for (int t = 0; t < nK; ++t) {
    const int buf = t & 1, nbuf = buf ^ 1;
    const bool pre = (t + 1 < nK);
    const int nk64 = (t + 1) * 64;
    s16x8 af[4], bfr[4];
    // P1: kk0 A m0-3 + B; stage Ak0(t+1)
#pragma unroll
    for (int m = 0; m < 4; ++m)
      af[m] = *(const s16x8*)&As[buf][(wr * 8 + m) * 512 + lo];
#pragma unroll
    for (int n = 0; n < 4; ++n)
      bfr[n] = *(const s16x8*)&Bs[buf][(wc * 4 + n) * 512 + lo];
    if (pre) {
      gload16(A + aoff[0] + nk64, &As[nbuf][ldso[0]]);
      gload16(A + aoff[1] + nk64, &As[nbuf][ldso[1]]);
    }
    __builtin_amdgcn_s_barrier();
    __builtin_amdgcn_s_setprio(1);
#pragma unroll
    for (int m = 0; m < 4; ++m)
#pragma unroll
      for (int n = 0; n < 4; ++n)
        acc[m][n] = __builtin_amdgcn_mfma_f32_16x16x32_bf16(af[m], bfr[n],
                                                            acc[m][n], 0, 0, 0);
    __builtin_amdgcn_s_setprio(0);
    __builtin_amdgcn_s_barrier();
    // P2: kk0 A m4-7; stage Bk0(t+1)
#pragma unroll
    for (int m = 0; m < 4; ++m)
      af[m] = *(const s16x8*)&As[buf][(wr * 8 + 4 + m) * 512 + lo];
    if (pre) {
      gload16(Bt + boff[0] + nk64, &Bs[nbuf][ldso[0]]);
      gload16(Bt + boff[1] + nk64, &Bs[nbuf][ldso[1]]);
    }
    __builtin_amdgcn_s_barrier();
    __builtin_amdgcn_s_setprio(1);
#pragma unroll
    for (int m = 0; m < 4; ++m)
#pragma unroll
      for (int n = 0; n < 4; ++n)
        acc[m + 4][n] = __builtin_amdgcn_mfma_f32_16x16x32_bf16(
            af[m], bfr[n], acc[m + 4][n], 0, 0, 0);
    __builtin_amdgcn_s_setprio(0);
    __builtin_amdgcn_s_barrier();
    // P3: kk1 A m0-3 + B; stage Ak1(t+1); gate kk1(t)
#pragma unroll
    for (int m = 0; m < 4; ++m)
      af[m] = *(const s16x8*)&As[buf][8192 + (wr * 8 + m) * 512 + lo];
#pragma unroll
    for (int n = 0; n < 4; ++n)
      bfr[n] = *(const s16x8*)&Bs[buf][8192 + (wc * 4 + n) * 512 + lo];
    if (pre) {
      gload16(A + aoff[2] + nk64, &As[nbuf][ldso[2]]);
      gload16(A + aoff[3] + nk64, &As[nbuf][ldso[3]]);
      asm volatile("s_waitcnt vmcnt(6)" ::: "memory");
    } else {
      asm volatile("s_waitcnt vmcnt(0)" ::: "memory");
    }
    __builtin_amdgcn_s_barrier();
    __builtin_amdgcn_s_setprio(1);
#pragma unroll
    for (int m = 0; m < 4; ++m)
#pragma unroll
      for (int n = 0; n < 4; ++n)
        acc[m][n] = __builtin_amdgcn_mfma_f32_16x16x32_bf16(af[m], bfr[n],
                                                            acc[m][n], 0, 0, 0);
    __builtin_amdgcn_s_setprio(0);
    __builtin_amdgcn_s_barrier();
    // P4: kk1 A m4-7; stage Bk1(t+1); gate kk0(t+1)
#pragma unroll
    for (int m = 0; m < 4; ++m)
      af[m] = *(const s16x8*)&As[buf][8192 + (wr * 8 + 4 + m) * 512 + lo];
    if (pre) {
      gload16(Bt + boff[2] + nk64, &Bs[nbuf][ldso[2]]);
      gload16(Bt + boff[3] + nk64, &Bs[nbuf][ldso[3]]);
      asm volatile("s_waitcnt vmcnt(4)" ::: "memory");
    }
    __builtin_amdgcn_s_barrier();
    __builtin_amdgcn_s_setprio(1);
#pragma unroll
    for (int m = 0; m < 4; ++m)
#pragma unroll
      for (int n = 0; n < 4; ++n)
        acc[m + 4][n] = __builtin_amdgcn_mfma_f32_16x16x32_bf16(
            af[m], bfr[n], acc[m + 4][n], 0, 0, 0);
    __builtin_amdgcn_s_setprio(0);
    __builtin_amdgcn_s_barrier();
  }
  float bv[4];
#pragma unroll
  for (int n = 0; n < 4; ++n)
    bv[n] = HAS_BIAS ? bias[nb + wc * 64 + n * 16 + lm] : 0.0f;
#pragma unroll
  for (int m = 0; m < 8; ++m) {
#pragma unroll
    for (int r = 0; r < 4; ++r) {
      int row = mb + wr * 128 + m * 16 + lg * 4 + r;
#pragma unroll
      for (int n = 0; n < 4; ++n) {
        int col = nb + wc * 64 + n * 16 + lm;
        float v = acc[m][n][r] + bv[n];
        if (HAS_RES) v += Res[(size_t)row * N + col];
        if (RELU) v = v > 0.f ? v : 0.f;
        if (OUT_BF16)
          Cb[(size_t)row * N + col] = f2bf(v);
        else
          Cf[(size_t)row * N + col] = v;
      }
    }
  }
}

// ---------- lm_head GEMM: 256x256 tile, 1024 thr, 3-stage ring ----------
__global__ __launch_bounds__(1024) void k_lmhead(
    const u16* __restrict__ A, const u16* __restrict__ Bt,
    const float* __restrict__ bias, float* __restrict__ Cf,
    float* __restrict__ Pp, int M, int N, int K) {
  __shared__ u16 As[3][8192];   // 256 x 32
  __shared__ u16 Bs[3][8192];   // 256 x 32
  const int tid = threadIdx.x;
  const int lane = tid & 63, wid = tid >> 6;
  const int lm = lane & 15, lg = lane >> 4;
  const int wr = wid >> 2, wc = wid & 3;

  unsigned nbx = gridDim.x;   // 125
  unsigned My = gridDim.y;    // 16
  unsigned nwg = nbx * My;    // 2000 (%8 == 0)
  unsigned orig = blockIdx.y * nbx + blockIdx.x;
  unsigned xcd = orig & 7u, idx = orig >> 3;
  unsigned g = xcd * (nwg >> 3) + idx;
  const int mb = (int)(g % My) * 256;
  const int nb = (int)(g / My) * 256;

  int rblk = tid >> 6, rem = tid & 63;
  int row16 = rem >> 2, psl = rem & 3;
  int sl = psl ^ ((row16 >> 1) & 3);
  int grow = rblk * 16 + row16;
  const int aoff = (mb + grow) * K + sl * 8;
  const int boff = (nb + grow) * K + sl * 8;
  const int lds = wid * 512;
  const int lo = lm * 32 + ((lg ^ ((lm >> 1) & 3)) << 3);

  f32x4 acc[4][4];
#pragma unroll
  for (int i = 0; i < 4; ++i)
#pragma unroll
    for (int j = 0; j < 4; ++j) acc[i][j] = f32x4{0.f, 0.f, 0.f, 0.f};

  auto stage = [&](int t, int s) {
    int ko = t * 32;
    gload16(A + aoff + ko, &As[s][lds]);
    gload16(Bt + boff + ko, &Bs[s][lds]);
  };

  const int nK = K >> 5;  // 32
  stage(0, 0);
  stage(1, 1);
  for (int t = 0; t < nK; ++t) {
    int s = t % 3;
    if (t + 1 < nK)
      asm volatile("s_waitcnt vmcnt(2)" ::: "memory");
    else
      asm volatile("s_waitcnt vmcnt(0)" ::: "memory");
    __builtin_amdgcn_s_barrier();
    s16x8 af[4], bfr[4];
#pragma unroll
    for (int m = 0; m < 4; ++m)
      af[m] = *(const s16x8*)&As[s][(wr * 4 + m) * 512 + lo];
#pragma unroll
    for (int n = 0; n < 4; ++n)
      bfr[n] = *(const s16x8*)&Bs[s][(wc * 4 + n) * 512 + lo];
    if (t + 2 < nK) stage(t + 2, (t + 2) % 3);
    __builtin_amdgcn_s_setprio(1);
#pragma unroll
    for (int m = 0; m < 4; ++m)
#pragma unroll
      for (int n = 0; n < 4; ++n)
        acc[m][n] = __builtin_amdgcn_mfma_f32_16x16x32_bf16(af[m], bfr[n],
                                                            acc[m][n], 0, 0, 0);
    __builtin_amdgcn_s_setprio(0);
  }
  float bv[4];
#pragma unroll
  for (int n = 0; n < 4; ++n) bv[n] = bias[nb + wc * 64 + n * 16 + lm];
#pragma unroll
  for (int m = 0; m < 4; ++m) {
#pragma unroll
    for (int r = 0; r < 4; ++r) {
      int row = mb + wr * 64 + m * 16 + lg * 4 + r;
#pragma unroll
      for (int n = 0; n < 4; ++n) {
        int col = nb + wc * 64 + n * 16 + lm;
        Cf[(size_t)row * N + col] = acc[m][n][r] + bv[n];
      }
    }
  }
  __syncthreads();
  float* redS = (float*)&As[0][0];
  float Sx[4][4];
#pragma unroll
  for (int m = 0; m < 4; ++m)
#pragma unroll
    for (int r = 0; r < 4; ++r)
      Sx[m][r] = __expf(acc[m][0][r] + bv[0]) + __expf(acc[m][1][r] + bv[1]) +
                 __expf(acc[m][2][r] + bv[2]) + __expf(acc[m][3][r] + bv[3]);
#pragma unroll
  for (int d = 1; d < 16; d <<= 1)
#pragma unroll
    for (int m = 0; m < 4; ++m)
#pragma unroll
      for (int r = 0; r < 4; ++r) Sx[m][r] += __shfl_xor(Sx[m][r], d, 16);
  if (lm == 0) {
#pragma unroll
    for (int m = 0; m < 4; ++m)
#pragma unroll
      for (int r = 0; r < 4; ++r)
        redS[(wr * 64 + m * 16 + lg * 4 + r) * 4 + wc] = Sx[m][r];
  }
  __syncthreads();
  if (tid < 256) {
    float srow = redS[tid * 4 + 0] + redS[tid * 4 + 1] + redS[tid * 4 + 2] +
                 redS[tid * 4 + 3];
    Pp[(size_t)(nb >> 8) * M + mb + tid] = srow;
  }
}

// ---------- flash attention v7: paired q-tiles, dbuf, MAX-FREE softmax ----
__global__ __launch_bounds__(256) void k_attn(
    const u16* __restrict__ qkv, const u16* __restrict__ vt,
    u16* __restrict__ o) {
  constexpr int PP = 72;
  __shared__ u16 Ks[2][64 * 64];
  __shared__ u16 Vs[2][64 * 64];
  __shared__ u16 Ps[4][16 * PP];
  int bid = blockIdx.x;  // p | h | b
  int p = bid & 7, h = (bid >> 3) & 15, b = bid >> 7;
  int tid = threadIdx.x, lane = tid & 63, wid = tid >> 6;
  int lm = lane & 15, lg = lane >> 4;
  const size_t rowbase = (size_t)b * T * C3 + (size_t)h * HS;
  const u16* kbase = qkv + rowbase + C;
  const u16* vbase = vt + (size_t)(b * H + h) * HS * T;
  const size_t obase = (size_t)b * T * C + (size_t)h * HS;
  const float scale = 0.125f;
  const int sr = tid >> 3, scs = (tid & 7) ^ (sr & 7);
  const int swz0 = (lg ^ (lm & 7)) * 8;
  const int swz1 = ((4 + lg) ^ (lm & 7)) * 8;
  const short one_bf = (short)0x3F80;  // bf16 1.0
  s16x8 ones;
#pragma unroll
  for (int j = 0; j < 8; ++j) ones[j] = one_bf;

  for (int qi = 0; qi < 2; ++qi) {
    int qt = qi ? (15 - p) : p;
    int qw = qt * 64 + wid * 16;
    s16x8 qf[2];
#pragma unroll
    for (int s = 0; s < 2; ++s)
      qf[s] = *(const s16x8*)&qkv[rowbase + (size_t)(qw + lm) * C3 + s * 32 +
                                  lg * 8];
    f32x4 lacc = f32x4{0.f, 0.f, 0.f, 0.f};
    f32x4 oacc[4];
#pragma unroll
    for (int n = 0; n < 4; ++n) oacc[n] = f32x4{0.f, 0.f, 0.f, 0.f};

    // prologue: stage tile 0 into buffer 0
    gload16(kbase + (size_t)sr * C3 + scs * 8, &Ks[0][wid * 512]);
    gload16(kbase + (size_t)(sr + 32) * C3 + scs * 8, &Ks[0][2048 + wid * 512]);
    gload16(vbase + (size_t)sr * T + scs * 8, &Vs[0][wid * 512]);
    gload16(vbase + (size_t)(sr + 32) * T + scs * 8, &Vs[0][2048 + wid * 512]);

    for (int kt = 0; kt <= qt; ++kt) {
      int buf = kt & 1;
      bool pre = kt < qt;
      if (pre) {  // stage kt+1 into the other buffer
        int nk = (kt + 1) * 64;
        int nbuf = buf ^ 1;
        gload16(kbase + (size_t)(nk + sr) * C3 + scs * 8, &Ks[nbuf][wid * 512]);
        gload16(kbase + (size_t)(nk + sr + 32) * C3 + scs * 8,
                &Ks[nbuf][2048 + wid * 512]);
        gload16(vbase + (size_t)sr * T + nk + scs * 8, &Vs[nbuf][wid * 512]);
        gload16(vbase + (size_t)(sr + 32) * T + nk + scs * 8,
                &Vs[nbuf][2048 + wid * 512]);
        asm volatile("s_waitcnt vmcnt(4)" ::: "memory");
      } else {
        asm volatile("s_waitcnt vmcnt(0)" ::: "memory");
      }
      __builtin_amdgcn_s_barrier();

      f32x4 s[4];
#pragma unroll
      for (int ch = 0; ch < 4; ++ch) {
        s16x8 k0 = *(const s16x8*)&Ks[buf][(ch * 16 + lm) * 64 + swz0];
        s16x8 k1 = *(const s16x8*)&Ks[buf][(ch * 16 + lm) * 64 + swz1];
        s[ch] = f32x4{0.f, 0.f, 0.f, 0.f};
        s[ch] = __builtin_amdgcn_mfma_f32_16x16x32_bf16(qf[0], k0, s[ch], 0, 0, 0);
        s[ch] = __builtin_amdgcn_mfma_f32_16x16x32_bf16(qf[1], k1, s[ch], 0, 0, 0);
      }
      // max-free: exp(s*scale) directly; mask -> 0
      if (kt == qt) {  // diagonal tile: mask
#pragma unroll
        for (int ch = 0; ch < 4; ++ch) {
          int col = kt * 64 + ch * 16 + lm;
#pragma unroll
          for (int r = 0; r < 4; ++r) {
            int row = qw + lg * 4 + r;
            s[ch][r] = (col <= row) ? __expf(s[ch][r] * scale) : 0.f;
          }
        }
      } else {
#pragma unroll
        for (int ch = 0; ch < 4; ++ch)
#pragma unroll
          for (int r = 0; r < 4; ++r) s[ch][r] = __expf(s[ch][r] * scale);
      }
      // P -> bf16 via per-wave LDS transpose
#pragma unroll
      for (int r = 0; r < 4; ++r) {
        int pr = lg * 4 + r;
#pragma unroll
        for (int ch = 0; ch < 4; ++ch)
          Ps[wid][pr * PP + ch * 16 + lm] = f2bf(s[ch][r]);
      }
      s16x8 pa0 = *(const s16x8*)&Ps[wid][lm * PP + lg * 8];
      s16x8 pa1 = *(const s16x8*)&Ps[wid][lm * PP + 32 + lg * 8];
      // row-sum via ones-MFMA
      lacc = __builtin_amdgcn_mfma_f32_16x16x32_bf16(pa0, ones, lacc, 0, 0, 0);
      lacc = __builtin_amdgcn_mfma_f32_16x16x32_bf16(pa1, ones, lacc, 0, 0, 0);
#pragma unroll
      for (int n = 0; n < 4; ++n) {
        s16x8 v0 = *(const s16x8*)&Vs[buf][(n * 16 + lm) * 64 + swz0];
        s16x8 v1 = *(const s16x8*)&Vs[buf][(n * 16 + lm) * 64 + swz1];
        oacc[n] =
            __builtin_amdgcn_mfma_f32_16x16x32_bf16(pa0, v0, oacc[n], 0, 0, 0);
        oacc[n] =
            __builtin_amdgcn_mfma_f32_16x16x32_bf16(pa1, v1, oacc[n], 0, 0, 0);
      }
      __builtin_amdgcn_s_barrier();  // all reads of buf done before overwrite
    }
    float inv[4];
#pragma unroll
    for (int r = 0; r < 4; ++r) inv[r] = 1.0f / lacc[r];
#pragma unroll
    for (int n = 0; n < 4; ++n)
#pragma unroll
      for (int r = 0; r < 4; ++r)
        o[obase + (size_t)(qw + lg * 4 + r) * C + n * 16 + lm] =
            f2bf(oacc[n][r] * inv[r]);
  }
}

// ---------- LayerNorm (vectorized: one float4 per thread) ----------
__global__ __launch_bounds__(256) void k_ln(
    const float* __restrict__ in, const float* __restrict__ g,
    const float* __restrict__ bsh, float* __restrict__ xout,
    u16* __restrict__ xbout) {
  int row = blockIdx.x;
  int tid = threadIdx.x;
  f32x4 v = ((const f32x4*)(in + (size_t)row * C))[tid];
  float s = v[0] + v[1] + v[2] + v[3];
  s = blockReduceSum(s);
  float mean = s * (1.0f / C);
  float s2 = 0.f;
#pragma unroll
  for (int j = 0; j < 4; ++j) {
    float d = v[j] - mean;
    s2 += d * d;
  }
  s2 = blockReduceSum(s2);
  float rstd = rsqrtf(s2 * (1.0f / C) + 1e-5f);
  f32x4 gv = ((const f32x4*)g)[tid];
  f32x4 bv = ((const f32x4*)bsh)[tid];
  f32x4 y;
  s16x4 yb;
#pragma unroll
  for (int j = 0; j < 4; ++j) {
    y[j] = (v[j] - mean) * rstd * gv[j] + bv[j];
    yb[j] = (short)f2bf(y[j]);
  }
  ((f32x4*)(xout + (size_t)row * C))[tid] = y;
  ((s16x4*)(xbout + (size_t)row * C))[tid] = yb;
}

// ---------- loss: merge per-block exp-sums + target logit ----------
__global__ __launch_bounds__(128) void k_rowloss2(
    const float* __restrict__ sums, const float* __restrict__ logits,
    const int* __restrict__ tgt, float* __restrict__ rowloss) {
  int row = blockIdx.x;
  int tid = threadIdx.x;
  float s = (tid < 125) ? sums[(size_t)tid * BT + row] : 0.f;
#pragma unroll
  for (int d = 1; d < 64; d <<= 1) s += __shfl_xor(s, d, 64);
  __shared__ float ss[2];
  if ((tid & 63) == 0) ss[tid >> 6] = s;
  __syncthreads();
  if (tid == 0)
    rowloss[row] = logf(ss[0] + ss[1]) - logits[(size_t)row * V + tgt[row]];
}

__global__ __launch_bounds__(256) void k_lossreduce(
    const float* __restrict__ rowloss, float* __restrict__ out) {
  __shared__ float red[256];
  int tid = threadIdx.x;
  float s = 0.f;
  for (int i = tid; i < BT; i += 256) s += rowloss[i];
  red[tid] = s;
  __syncthreads();
  for (int m = 128; m >= 1; m >>= 1) {
    if (tid < m) red[tid] += red[tid + m];
    __syncthreads();
  }
  if (tid == 0) out[0] = red[0] * (1.0f / BT);
}

// ---------------- host orchestration ----------------
extern "C" void kernel_launch(void* const* d_in, const int* in_sizes, int n_in,
                              void* d_out, int out_size, void* d_ws,
                              size_t ws_size, hipStream_t stream) {
  (void)in_sizes; (void)n_in; (void)out_size; (void)ws_size;
  const int* index = (const int*)d_in[0];
  const int* targets = (const int*)d_in[1];
  const float* tok_emb = (const float*)d_in[2];
  const float* pos_emb = (const float*)d_in[3];
  const float* wq = (const float*)d_in[4];
  const float* wk = (const float*)d_in[5];
  const float* wv = (const float*)d_in[6];
  const float* wo = (const float*)d_in[7];
  const float* bo = (const float*)d_in[8];
  const float* w1 = (const float*)d_in[9];
  const float* b1 = (const float*)d_in[10];
  const float* w2 = (const float*)d_in[11];
  const float* b2 = (const float*)d_in[12];
  const float* ln1_g = (const float*)d_in[13];
  const float* ln1_b = (const float*)d_in[14];
  const float* ln2_g = (const float*)d_in[15];
  const float* ln2_b = (const float*)d_in[16];
  const float* lnf_g = (const float*)d_in[17];
  const float* lnf_b = (const float*)d_in[18];
  const float* lm_w = (const float*)d_in[19];
  const float* lm_b = (const float*)d_in[20];

  float* logits = (float*)d_out;
  float* loss = logits + (size_t)BT * V;

  size_t off = 0;
  auto alloc = [&](size_t bytes) -> void* {
    off = (off + 255) & ~(size_t)255;
    void* p = (void*)((char*)d_ws + off);
    off += bytes;
    return p;
  };
  u16* wqkv_t = (u16*)alloc((size_t)L * C3 * C * 2);  // [L][3C][C]
  u16* wo_t = (u16*)alloc((size_t)L * C * C * 2);
  u16* w1_t = (u16*)alloc((size_t)L * C * C4 * 2);
  u16* w2_t = (u16*)alloc((size_t)L * C4 * C * 2);
  u16* lmw_t = (u16*)alloc((size_t)V * C * 2);
  float* x = (float*)alloc((size_t)BT * C * 4);
  float* tmp = (float*)alloc((size_t)BT * C * 4);
  u16* xb = (u16*)alloc((size_t)BT * C * 2);
  u16* qkvb = (u16*)alloc((size_t)BT * C3 * 2);
  u16* vtb = (u16*)alloc((size_t)BT * C * 2);   // V transposed per (b,h)
  u16* attb = (u16*)alloc((size_t)BT * C * 2);
  u16* hb = (u16*)alloc((size_t)BT * C4 * 2);
  float* rowloss = (float*)alloc((size_t)BT * 4);
  float* sums = (float*)alloc((size_t)BT * 128 * 4);

  dim3 blk(256);
  dim3 blk5(512);
  k_transpose<<<dim3(C / 64, C / 64, L), blk, 0, stream>>>(
      wq, wqkv_t, C, C, (size_t)C * C, (size_t)C3 * C);
  k_transpose<<<dim3(C / 64, C / 64, L), blk, 0, stream>>>(
      wk, wqkv_t + (size_t)C * C, C, C, (size_t)C * C, (size_t)C3 * C);
  k_transpose<<<dim3(C / 64, C / 64, L), blk, 0, stream>>>(
      wv, wqkv_t + (size_t)2 * C * C, C, C, (size_t)C * C, (size_t)C3 * C);
  k_transpose<<<dim3(C / 64, C / 64, L), blk, 0, stream>>>(
      wo, wo_t, C, C, (size_t)C * C, (size_t)C * C);
  k_transpose<<<dim3(C4 / 64, C / 64, L), blk, 0, stream>>>(
      w1, w1_t, C, C4, (size_t)C * C4, (size_t)C * C4);
  k_transpose<<<dim3(C / 64, C4 / 64, L), blk, 0, stream>>>(
      w2, w2_t, C4, C, (size_t)C4 * C, (size_t)C4 * C);
  k_transpose<<<dim3(V / 64, C / 64, 1), blk, 0, stream>>>(
      lm_w, lmw_t, C, V, 0, 0);

  k_embed<<<BT, blk, 0, stream>>>(index, tok_emb, pos_emb, x, xb);

  dim3 gQKV(C3 / 128, BT / 128);   // 768 wg (128^2 ring, VT)
  dim3 gCC(C / 128, BT / 128);     // 256 wg (128^2 ring)
  dim3 gC4(C4 / 256, BT / 256);    // 256 wg (256^2 8-phase)
  for (int l = 0; l < L; ++l) {
    const u16* wqkvt = wqkv_t + (size_t)l * C3 * C;
    const u16* wot = wo_t + (size_t)l * C * C;
    const u16* w1t = w1_t + (size_t)l * C * C4;
    const u16* w2t = w2_t + (size_t)l * C4 * C;

    k_gemm<1, 0, 0, 0, 1><<<gQKV, blk, 0, stream>>>(
        xb, wqkvt, nullptr, nullptr, nullptr, qkvb, vtb, BT, C3, C);
    k_attn<<<B * H * 8, blk, 0, stream>>>(qkvb, vtb, attb);
    k_gemm<0, 0, 1, 1, 0><<<gCC, blk, 0, stream>>>(
        attb, wot, bo + (size_t)l * C, x, tmp, nullptr, nullptr, BT, C, C);
    k_ln<<<BT, blk, 0, stream>>>(tmp, ln1_g + (size_t)l * C,
                                 ln1_b + (size_t)l * C, x, xb);
    k_gemm256<1, 1, 1, 0><<<gC4, blk5, 0, stream>>>(
        xb, w1t, b1 + (size_t)l * C4, nullptr, nullptr, hb, BT, C4, C);
    k_gemm<0, 0, 1, 1, 0><<<gCC, blk, 0, stream>>>(
        hb, w2t, b2 + (size_t)l * C, x, tmp, nullptr, nullptr, BT, C, C4);
    k_ln<<<BT, blk, 0, stream>>>(tmp, ln2_g + (size_t)l * C,
                                 ln2_b + (size_t)l * C, x, xb);
  }
  k_ln<<<BT, blk, 0, stream>>>(x, lnf_g, lnf_b, x, xb);
  k_lmhead<<<dim3(V / 256, BT / 256), dim3(1024), 0, stream>>>(
      xb, lmw_t, lm_b, logits, sums, BT, V, C);
  k_rowloss2<<<BT, dim3(128), 0, stream>>>(sums, logits, targets, rowloss);
  k_lossreduce<<<1, blk, 0, stream>>>(rowloss, loss);
}

// Round 17
// 2359.927 us; speedup vs baseline: 1.0033x; 1.0033x over previous
//
#include <hip/hip_runtime.h>

typedef unsigned short u16;
typedef __attribute__((ext_vector_type(4))) float f32x4;
typedef __attribute__((ext_vector_type(8))) short s16x8;
typedef __attribute__((ext_vector_type(4))) short s16x4;

static constexpr int V = 32000;
static constexpr int C = 1024;
static constexpr int T = 1024;
static constexpr int H = 16;
static constexpr int L = 8;
static constexpr int B = 4;
static constexpr int HS = 64;
static constexpr int BT = B * T;   // 4096
static constexpr int C4 = 4 * C;   // 4096
static constexpr int C3 = 3 * C;   // 3072

__device__ __forceinline__ u16 f2bf(float f) {
  union { float f; unsigned u; } v; v.f = f;
  unsigned r = v.u + 0x7fffu + ((v.u >> 16) & 1u);
  return (u16)(r >> 16);
}

__device__ __forceinline__ void gload16(const u16* g, u16* l) {
  __builtin_amdgcn_global_load_lds(
      (const __attribute__((address_space(1))) void*)g,
      (__attribute__((address_space(3))) void*)l, 16, 0, 0);
}

// ---------- block reduction (256 threads) ----------
__device__ __forceinline__ float blockReduceSum(float v) {
  __shared__ float red[4];
  int lane = threadIdx.x & 63, w = threadIdx.x >> 6;
#pragma unroll
  for (int m = 32; m >= 1; m >>= 1) v += __shfl_xor(v, m, 64);
  if (lane == 0) red[w] = v;
  __syncthreads();
  float r = red[0] + red[1] + red[2] + red[3];
  __syncthreads();
  return r;
}

// ---------- embed (vectorized: one float4 per thread) ----------
__global__ __launch_bounds__(256) void k_embed(
    const int* __restrict__ idx, const float* __restrict__ tok,
    const float* __restrict__ pos, float* __restrict__ x, u16* __restrict__ xb) {
  int bt = blockIdx.x;
  int t = bt & (T - 1);
  int row = idx[bt];
  int tid = threadIdx.x;
  f32x4 tv = ((const f32x4*)(tok + (size_t)row * C))[tid];
  f32x4 pv = ((const f32x4*)(pos + (size_t)t * C))[tid];
  f32x4 y;
  s16x4 yb;
#pragma unroll
  for (int j = 0; j < 4; ++j) {
    y[j] = tv[j] + pv[j];
    yb[j] = (short)f2bf(y[j]);
  }
  ((f32x4*)(x + (size_t)bt * C))[tid] = y;
  ((s16x4*)(xb + (size_t)bt * C))[tid] = yb;
}

// ---------- weight convert+transpose: fp32 [K,N] -> bf16 [N,K] ----------
__global__ __launch_bounds__(256) void k_transpose(
    const float* __restrict__ W, u16* __restrict__ Wt, int K, int N,
    size_t sW, size_t sWt) {
  __shared__ float tile[64][65];
  const float* Wz = W + sW * blockIdx.z;
  u16* Wtz = Wt + sWt * blockIdx.z;
  int n0 = blockIdx.x * 64, k0 = blockIdx.y * 64;
  int tc = threadIdx.x & 63, tr = threadIdx.x >> 6;
#pragma unroll
  for (int i = 0; i < 16; ++i) {
    int r = tr + i * 4;
    tile[r][tc] = Wz[(size_t)(k0 + r) * N + (n0 + tc)];
  }
  __syncthreads();
#pragma unroll
  for (int i = 0; i < 16; ++i) {
    int r = tr + i * 4;  // n-offset within tile
    Wtz[(size_t)(n0 + r) * K + (k0 + tc)] = f2bf(tile[tc][r]);
  }
}

// ---------- GEMM 128x128, 3-stage ring + T2 swizzle ----------
// VT=1 (QKV): blocks with nb>=2C write V projection transposed into Vtp.
template <int OUT_BF16, int RELU, int HAS_BIAS, int HAS_RES, int VT>
__global__ __launch_bounds__(256, 2) void k_gemm(
    const u16* __restrict__ A, const u16* __restrict__ Bt,
    const float* __restrict__ bias, const float* __restrict__ Res,
    float* __restrict__ Cf, u16* __restrict__ Cb, u16* __restrict__ Vtp,
    int M, int N, int K) {
  __shared__ u16 As[3][4096];
  __shared__ u16 Bs[3][4096];
  int tid = threadIdx.x;
  int lane = tid & 63, wid = tid >> 6;
  int lm = lane & 15, lg = lane >> 4;
  int wm = wid >> 1, wn = wid & 1;

  unsigned nbx = gridDim.x;
  unsigned nwg = nbx * gridDim.y;
  unsigned orig = blockIdx.y * nbx + blockIdx.x;
  unsigned f = ((nwg & 7u) == 0u) ? (orig & 7u) * (nwg >> 3) + (orig >> 3) : orig;
  int mb = (int)(f / nbx) * 128, nb = (int)(f % nbx) * 128;

  f32x4 acc[4][4];
#pragma unroll
  for (int i = 0; i < 4; ++i)
#pragma unroll
    for (int j = 0; j < 4; ++j) acc[i][j] = f32x4{0.f, 0.f, 0.f, 0.f};

  int row = tid >> 2, psl = tid & 3;
  int sl = psl ^ (((row & 15) >> 1) & 3);
  const u16* a0 = A + (size_t)(mb + row) * K + sl * 8;
  const u16* a1 = A + (size_t)(mb + 64 + row) * K + sl * 8;
  const u16* b0 = Bt + (size_t)(nb + row) * K + sl * 8;
  const u16* b1 = Bt + (size_t)(nb + 64 + row) * K + sl * 8;
  const int ld0 = wid * 512, ld1 = 2048 + wid * 512;
  const int lo = lm * 32 + ((lg ^ ((lm >> 1) & 3)) << 3);

  auto stage = [&](int t, int s) {
    int ko = t * 32;
    gload16(a0 + ko, &As[s][ld0]);
    gload16(a1 + ko, &As[s][ld1]);
    gload16(b0 + ko, &Bs[s][ld0]);
    gload16(b1 + ko, &Bs[s][ld1]);
  };

  int nK = K >> 5;
  stage(0, 0);
  stage(1, 1);
  for (int t = 0; t < nK; ++t) {
    int s = t % 3;
    if (t + 1 < nK)
      asm volatile("s_waitcnt vmcnt(4)" ::: "memory");
    else
      asm volatile("s_waitcnt vmcnt(0)" ::: "memory");
    __builtin_amdgcn_s_barrier();
    s16x8 af[4], bfr[4];
#pragma unroll
    for (int m = 0; m < 4; ++m)
      af[m] = *(const s16x8*)&As[s][(wm * 4 + m) * 512 + lo];
#pragma unroll
    for (int n = 0; n < 4; ++n)
      bfr[n] = *(const s16x8*)&Bs[s][(wn * 4 + n) * 512 + lo];
    if (t + 2 < nK) stage(t + 2, (t + 2) % 3);
    __builtin_amdgcn_s_setprio(1);
#pragma unroll
    for (int m = 0; m < 4; ++m)
#pragma unroll
      for (int n = 0; n < 4; ++n)
        acc[m][n] = __builtin_amdgcn_mfma_f32_16x16x32_bf16(af[m], bfr[n],
                                                            acc[m][n], 0, 0, 0);
    __builtin_amdgcn_s_setprio(0);
  }
  if (VT && nb >= 2 * C) {
    // V projection: write transposed [d][t] per (b,h); wave's 64 cols = 1 head
    int hh = ((nb + wn * 64) - 2 * C) >> 6;
#pragma unroll
    for (int m = 0; m < 4; ++m) {
      int t0 = mb + wm * 64 + m * 16 + lg * 4;
      int bb = t0 >> 10, tt = t0 & (T - 1);
      size_t vbase = ((size_t)(bb * H + hh) * HS) * T + tt;
#pragma unroll
      for (int n = 0; n < 4; ++n) {
        int d = n * 16 + lm;
        s16x4 pk;
#pragma unroll
        for (int r = 0; r < 4; ++r) pk[r] = (short)f2bf(acc[m][n][r]);
        *(s16x4*)&Vtp[vbase + (size_t)d * T] = pk;
      }
    }
    return;
  }
#pragma unroll
  for (int m = 0; m < 4; ++m) {
#pragma unroll
    for (int n = 0; n < 4; ++n) {
      int col = nb + wn * 64 + n * 16 + lm;
      float bv = HAS_BIAS ? bias[col] : 0.0f;
#pragma unroll
      for (int r = 0; r < 4; ++r) {
        int rw = mb + wm * 64 + m * 16 + lg * 4 + r;
        float v = acc[m][n][r] + bv;
        if (HAS_RES) v += Res[(size_t)rw * N + col];
        if (RELU) v = v > 0.f ? v : 0.f;
        if (OUT_BF16)
          Cb[(size_t)rw * N + col] = f2bf(v);
        else
          Cf[(size_t)rw * N + col] = v;
      }
    }
  }
}

// ---------- GEMM 256x256 8-phase (T2+T3+T4+T5) for w1 ----------
template <int OUT_BF16, int RELU, int HAS_BIAS, int HAS_RES>
__global__ __launch_bounds__(512) void k_gemm256(
    const u16* __restrict__ A, const u16* __restrict__ Bt,
    const float* __restrict__ bias, const float* __restrict__ Res,
    float* __restrict__ Cf, u16* __restrict__ Cb, int M, int N, int K) {
  __shared__ u16 As[2][16384];
  __shared__ u16 Bs[2][16384];
  const int tid = threadIdx.x;
  const int lane = tid & 63, wid = tid >> 6;
  const int lm = lane & 15, lg = lane >> 4;
  const int wr = wid >> 2, wc = wid & 3;

  unsigned nbx = gridDim.x;
  unsigned nwg = nbx * gridDim.y;
  unsigned orig = blockIdx.y * nbx + blockIdx.x;
  unsigned f =
      ((nwg & 7u) == 0u) ? (orig & 7u) * (nwg >> 3) + (orig >> 3) : orig;
  const int mb = (int)(f / nbx) * 256;
  const int nb = (int)(f % nbx) * 256;

  int aoff[4], boff[4], ldso[4];
#pragma unroll
  for (int h = 0; h < 4; ++h) {
    const int kk = h >> 1, p = h & 1;
    int rem = p * 512 + tid;
    int rblk = rem >> 6;
    int rem2 = rem & 63;
    int row16 = rem2 >> 2, psl = rem2 & 3;
    int sl = psl ^ ((row16 >> 1) & 3);
    int grow = rblk * 16 + row16;
    int gk = kk * 32 + sl * 8;
    aoff[h] = (mb + grow) * K + gk;
    boff[h] = (nb + grow) * K + gk;
    ldso[h] = kk * 8192 + p * 4096 + wid * 512;
  }
  const int lo = lm * 32 + ((lg ^ ((lm >> 1) & 3)) << 3);

  f32x4 acc[8][4];
#pragma unroll
  for (int i = 0; i < 8; ++i)
#pragma unroll
    for (int j = 0; j < 4; ++j) acc[i][j] = f32x4{0.f, 0.f, 0.f, 0.f};

  const int nK = K >> 6;
  gload16(A + aoff[0], &As[0][ldso[0]]);
  gload16(A + aoff[1], &As[0][ldso[1]]);
  gload16(Bt + boff[0], &Bs[0][ldso[0]]);
  gload16(Bt + boff[1], &Bs[0][ldso[1]]);
  gload16(A + aoff[2], &As[0][ldso[2]]);
  gload16(A + aoff[3], &As[0][ldso[3]]);
  gload16(Bt + boff[2], &Bs[0][ldso[2]]);
  gload16(Bt + boff[3], &Bs[0][ldso[3]]);
  asm volatile("s_waitcnt vmcnt(4)" ::: "memory");
  __builtin_amdgcn_s_barrier();

  for (int t = 0; t < nK; ++t) {
    const int buf = t & 1, nbuf = buf ^ 1;
    const bool pre = (t + 1 < nK);
    const int nk64 = (t + 1) * 64;
    s16x8 af[4], bfr[4];
    // P1: kk0 A m0-3 + B; stage Ak0(t+1)
#pragma unroll
    for (int m = 0; m < 4; ++m)
      af[m] = *(const s16x8*)&As[buf][(wr * 8 + m) * 512 + lo];
#pragma unroll
    for (int n = 0; n < 4; ++n)
      bfr[n] = *(const s16x8*)&Bs[buf][(wc * 4 + n) * 512 + lo];
    if (pre) {
      gload16(A + aoff[0] + nk64, &As[nbuf][ldso[0]]);
      gload16(A + aoff[1] + nk64, &As[nbuf][ldso[1]]);
    }
    __builtin_amdgcn_s_barrier();
    __builtin_amdgcn_s_setprio(1);
#pragma unroll
    for (int m = 0; m < 4; ++m)
#pragma unroll
      for (int n = 0; n < 4; ++n)
        acc[m][n] = __builtin_amdgcn_mfma_f32_16x16x32_bf16(af[m], bfr[n],
                                                            acc[m][n], 0, 0, 0);
    __builtin_amdgcn_s_setprio(0);
    __builtin_amdgcn_s_barrier();
    // P2: kk0 A m4-7; stage Bk0(t+1)
#pragma unroll
    for (int m = 0; m < 4; ++m)
      af[m] = *(const s16x8*)&As[buf][(wr * 8 + 4 + m) * 512 + lo];
    if (pre) {
      gload16(Bt + boff[0] + nk64, &Bs[nbuf][ldso[0]]);
      gload16(Bt + boff[1] + nk64, &Bs[nbuf][ldso[1]]);
    }
    __builtin_amdgcn_s_barrier();
    __builtin_amdgcn_s_setprio(1);
#pragma unroll
    for (int m = 0; m < 4; ++m)
#pragma unroll
      for (int n = 0; n < 4; ++n)
        acc[m + 4][n] = __builtin_amdgcn_mfma_f32_16x16x32_bf16(
            af[m], bfr[n], acc[m + 4][n], 0, 0, 0);
    __builtin_amdgcn_s_setprio(0);
    __builtin_amdgcn_s_barrier();
    // P3: kk1 A m0-3 + B; stage Ak1(t+1); gate kk1(t)
#pragma unroll
    for (int m = 0; m < 4; ++m)
      af[m] = *(const s16x8*)&As[buf][8192 + (wr * 8 + m) * 512 + lo];
#pragma unroll
    for (int n = 0; n < 4; ++n)
      bfr[n] = *(const s16x8*)&Bs[buf][8192 + (wc * 4 + n) * 512 + lo];
    if (pre) {
      gload16(A + aoff[2] + nk64, &As[nbuf][ldso[2]]);
      gload16(A + aoff[3] + nk64, &As[nbuf][ldso[3]]);
      asm volatile("s_waitcnt vmcnt(6)" ::: "memory");
    } else {
      asm volatile("s_waitcnt vmcnt(0)" ::: "memory");
    }
    __builtin_amdgcn_s_barrier();
    __builtin_amdgcn_s_setprio(1);
#pragma unroll
    for (int m = 0; m < 4; ++m)
#pragma unroll
      for (int n = 0; n < 4; ++n)
        acc[m][n] = __builtin_amdgcn_mfma_f32_16x16x32_bf16(af[m], bfr[n],
                                                            acc[m][n], 0, 0, 0);
    __builtin_amdgcn_s_setprio(0);
    __builtin_amdgcn_s_barrier();
    // P4: kk1 A m4-7; stage Bk1(t+1); gate kk0(t+1)
#pragma unroll
    for (int m = 0; m < 4; ++m)
      af[m] = *(const s16x8*)&As[buf][8192 + (wr * 8 + 4 + m) * 512 + lo];
    if (pre) {
      gload16(Bt + boff[2] + nk64, &Bs[nbuf][ldso[2]]);
      gload16(Bt + boff[3] + nk64, &Bs[nbuf][ldso[3]]);
      asm volatile("s_waitcnt vmcnt(4)" ::: "memory");
    }
    __builtin_amdgcn_s_barrier();
    __builtin_amdgcn_s_setprio(1);
#pragma unroll
    for (int m = 0; m < 4; ++m)
#pragma unroll
      for (int n = 0; n < 4; ++n)
        acc[m + 4][n] = __builtin_amdgcn_mfma_f32_16x16x32_bf16(
            af[m], bfr[n], acc[m + 4][n], 0, 0, 0);
    __builtin_amdgcn_s_setprio(0);
    __builtin_amdgcn_s_barrier();
  }
  float bv[4];
#pragma unroll
  for (int n = 0; n < 4; ++n)
    bv[n] = HAS_BIAS ? bias[nb + wc * 64 + n * 16 + lm] : 0.0f;
#pragma unroll
  for (int m = 0; m < 8; ++m) {
#pragma unroll
    for (int r = 0; r < 4; ++r) {
      int row = mb + wr * 128 + m * 16 + lg * 4 + r;
#pragma unroll
      for (int n = 0; n < 4; ++n) {
        int col = nb + wc * 64 + n * 16 + lm;
        float v = acc[m][n][r] + bv[n];
        if (HAS_RES) v += Res[(size_t)row * N + col];
        if (RELU) v = v > 0.f ? v : 0.f;
        if (OUT_BF16)
          Cb[(size_t)row * N + col] = f2bf(v);
        else
          Cf[(size_t)row * N + col] = v;
      }
    }
  }
}

// ---------- lm_head GEMM: 256x256 tile, 1024 thr, 3-stage ring ----------
__global__ __launch_bounds__(1024) void k_lmhead(
    const u16* __restrict__ A, const u16* __restrict__ Bt,
    const float* __restrict__ bias, float* __restrict__ Cf,
    float* __restrict__ Pp, int M, int N, int K) {
  __shared__ u16 As[3][8192];   // 256 x 32
  __shared__ u16 Bs[3][8192];   // 256 x 32
  const int tid = threadIdx.x;
  const int lane = tid & 63, wid = tid >> 6;
  const int lm = lane & 15, lg = lane >> 4;
  const int wr = wid >> 2, wc = wid & 3;

  unsigned nbx = gridDim.x;   // 125
  unsigned My = gridDim.y;    // 16
  unsigned nwg = nbx * My;    // 2000 (%8 == 0)
  unsigned orig = blockIdx.y * nbx + blockIdx.x;
  unsigned xcd = orig & 7u, idx = orig >> 3;
  unsigned g = xcd * (nwg >> 3) + idx;
  const int mb = (int)(g % My) * 256;
  const int nb = (int)(g / My) * 256;

  int rblk = tid >> 6, rem = tid & 63;
  int row16 = rem >> 2, psl = rem & 3;
  int sl = psl ^ ((row16 >> 1) & 3);
  int grow = rblk * 16 + row16;
  const int aoff = (mb + grow) * K + sl * 8;
  const int boff = (nb + grow) * K + sl * 8;
  const int lds = wid * 512;
  const int lo = lm * 32 + ((lg ^ ((lm >> 1) & 3)) << 3);

  f32x4 acc[4][4];
#pragma unroll
  for (int i = 0; i < 4; ++i)
#pragma unroll
    for (int j = 0; j < 4; ++j) acc[i][j] = f32x4{0.f, 0.f, 0.f, 0.f};

  auto stage = [&](int t, int s) {
    int ko = t * 32;
    gload16(A + aoff + ko, &As[s][lds]);
    gload16(Bt + boff + ko, &Bs[s][lds]);
  };

  const int nK = K >> 5;  // 32
  stage(0, 0);
  stage(1, 1);
  for (int t = 0; t < nK; ++t) {
    int s = t % 3;
    if (t + 1 < nK)
      asm volatile("s_waitcnt vmcnt(2)" ::: "memory");
    else
      asm volatile("s_waitcnt vmcnt(0)" ::: "memory");
    __builtin_amdgcn_s_barrier();
    s16x8 af[4], bfr[4];
#pragma unroll
    for (int m = 0; m < 4; ++m)
      af[m] = *(const s16x8*)&As[s][(wr * 4 + m) * 512 + lo];
#pragma unroll
    for (int n = 0; n < 4; ++n)
      bfr[n] = *(const s16x8*)&Bs[s][(wc * 4 + n) * 512 + lo];
    if (t + 2 < nK) stage(t + 2, (t + 2) % 3);
    __builtin_amdgcn_s_setprio(1);
#pragma unroll
    for (int m = 0; m < 4; ++m)
#pragma unroll
      for (int n = 0; n < 4; ++n)
        acc[m][n] = __builtin_amdgcn_mfma_f32_16x16x32_bf16(af[m], bfr[n],
                                                            acc[m][n], 0, 0, 0);
    __builtin_amdgcn_s_setprio(0);
  }
  float bv[4];
#pragma unroll
  for (int n = 0; n < 4; ++n) bv[n] = bias[nb + wc * 64 + n * 16 + lm];
#pragma unroll
  for (int m = 0; m < 4; ++m) {
#pragma unroll
    for (int r = 0; r < 4; ++r) {
      int row = mb + wr * 64 + m * 16 + lg * 4 + r;
#pragma unroll
      for (int n = 0; n < 4; ++n) {
        int col = nb + wc * 64 + n * 16 + lm;
        Cf[(size_t)row * N + col] = acc[m][n][r] + bv[n];
      }
    }
  }
  __syncthreads();
  float* redS = (float*)&As[0][0];
  float Sx[4][4];
#pragma unroll
  for (int m = 0; m < 4; ++m)
#pragma unroll
    for (int r = 0; r < 4; ++r)
      Sx[m][r] = __expf(acc[m][0][r] + bv[0]) + __expf(acc[m][1][r] + bv[1]) +
                 __expf(acc[m][2][r] + bv[2]) + __expf(acc[m][3][r] + bv[3]);
#pragma unroll
  for (int d = 1; d < 16; d <<= 1)
#pragma unroll
    for (int m = 0; m < 4; ++m)
#pragma unroll
      for (int r = 0; r < 4; ++r) Sx[m][r] += __shfl_xor(Sx[m][r], d, 16);
  if (lm == 0) {
#pragma unroll
    for (int m = 0; m < 4; ++m)
#pragma unroll
      for (int r = 0; r < 4; ++r)
        redS[(wr * 64 + m * 16 + lg * 4 + r) * 4 + wc] = Sx[m][r];
  }
  __syncthreads();
  if (tid < 256) {
    float srow = redS[tid * 4 + 0] + redS[tid * 4 + 1] + redS[tid * 4 + 2] +
                 redS[tid * 4 + 3];
    Pp[(size_t)(nb >> 8) * M + mb + tid] = srow;
  }
}

// ---------- flash attention v7: paired q-tiles, dbuf, MAX-FREE softmax ----
__global__ __launch_bounds__(256) void k_attn(
    const u16* __restrict__ qkv, const u16* __restrict__ vt,
    u16* __restrict__ o) {
  constexpr int PP = 72;
  __shared__ u16 Ks[2][64 * 64];
  __shared__ u16 Vs[2][64 * 64];
  __shared__ u16 Ps[4][16 * PP];
  int bid = blockIdx.x;  // p | h | b
  int p = bid & 7, h = (bid >> 3) & 15, b = bid >> 7;
  int tid = threadIdx.x, lane = tid & 63, wid = tid >> 6;
  int lm = lane & 15, lg = lane >> 4;
  const size_t rowbase = (size_t)b * T * C3 + (size_t)h * HS;
  const u16* kbase = qkv + rowbase + C;
  const u16* vbase = vt + (size_t)(b * H + h) * HS * T;
  const size_t obase = (size_t)b * T * C + (size_t)h * HS;
  const float scale = 0.125f;
  const int sr = tid >> 3, scs = (tid & 7) ^ (sr & 7);
  const int swz0 = (lg ^ (lm & 7)) * 8;
  const int swz1 = ((4 + lg) ^ (lm & 7)) * 8;
  const short one_bf = (short)0x3F80;  // bf16 1.0
  s16x8 ones;
#pragma unroll
  for (int j = 0; j < 8; ++j) ones[j] = one_bf;

  for (int qi = 0; qi < 2; ++qi) {
    int qt = qi ? (15 - p) : p;
    int qw = qt * 64 + wid * 16;
    s16x8 qf[2];
#pragma unroll
    for (int s = 0; s < 2; ++s)
      qf[s] = *(const s16x8*)&qkv[rowbase + (size_t)(qw + lm) * C3 + s * 32 +
                                  lg * 8];
    f32x4 lacc = f32x4{0.f, 0.f, 0.f, 0.f};
    f32x4 oacc[4];
#pragma unroll
    for (int n = 0; n < 4; ++n) oacc[n] = f32x4{0.f, 0.f, 0.f, 0.f};

    // prologue: stage tile 0 into buffer 0
    gload16(kbase + (size_t)sr * C3 + scs * 8, &Ks[0][wid * 512]);
    gload16(kbase + (size_t)(sr + 32) * C3 + scs * 8, &Ks[0][2048 + wid * 512]);
    gload16(vbase + (size_t)sr * T + scs * 8, &Vs[0][wid * 512]);
    gload16(vbase + (size_t)(sr + 32) * T + scs * 8, &Vs[0][2048 + wid * 512]);

    for (int kt = 0; kt <= qt; ++kt) {
      int buf = kt & 1;
      bool pre = kt < qt;
      if (pre) {  // stage kt+1 into the other buffer
        int nk = (kt + 1) * 64;
        int nbuf = buf ^ 1;
        gload16(kbase + (size_t)(nk + sr) * C3 + scs * 8, &Ks[nbuf][wid * 512]);
        gload16(kbase + (size_t)(nk + sr + 32) * C3 + scs * 8,
                &Ks[nbuf][2048 + wid * 512]);
        gload16(vbase + (size_t)sr * T + nk + scs * 8, &Vs[nbuf][wid * 512]);
        gload16(vbase + (size_t)(sr + 32) * T + nk + scs * 8,
                &Vs[nbuf][2048 + wid * 512]);
        asm volatile("s_waitcnt vmcnt(4)" ::: "memory");
      } else {
        asm volatile("s_waitcnt vmcnt(0)" ::: "memory");
      }
      __builtin_amdgcn_s_barrier();

      f32x4 s[4];
#pragma unroll
      for (int ch = 0; ch < 4; ++ch) {
        s16x8 k0 = *(const s16x8*)&Ks[buf][(ch * 16 + lm) * 64 + swz0];
        s16x8 k1 = *(const s16x8*)&Ks[buf][(ch * 16 + lm) * 64 + swz1];
        s[ch] = f32x4{0.f, 0.f, 0.f, 0.f};
        s[ch] = __builtin_amdgcn_mfma_f32_16x16x32_bf16(qf[0], k0, s[ch], 0, 0, 0);
        s[ch] = __builtin_amdgcn_mfma_f32_16x16x32_bf16(qf[1], k1, s[ch], 0, 0, 0);
      }
      // max-free: exp(s*scale) directly; mask -> 0
      if (kt == qt) {  // diagonal tile: mask
#pragma unroll
        for (int ch = 0; ch < 4; ++ch) {
          int col = kt * 64 + ch * 16 + lm;
#pragma unroll
          for (int r = 0; r < 4; ++r) {
            int row = qw + lg * 4 + r;
            s[ch][r] = (col <= row) ? __expf(s[ch][r] * scale) : 0.f;
          }
        }
      } else {
#pragma unroll
        for (int ch = 0; ch < 4; ++ch)
#pragma unroll
          for (int r = 0; r < 4; ++r) s[ch][r] = __expf(s[ch][r] * scale);
      }
      // P -> bf16 via per-wave LDS transpose
#pragma unroll
      for (int r = 0; r < 4; ++r) {
        int pr = lg * 4 + r;
#pragma unroll
        for (int ch = 0; ch < 4; ++ch)
          Ps[wid][pr * PP + ch * 16 + lm] = f2bf(s[ch][r]);
      }
      s16x8 pa0 = *(const s16x8*)&Ps[wid][lm * PP + lg * 8];
      s16x8 pa1 = *(const s16x8*)&Ps[wid][lm * PP + 32 + lg * 8];
      // row-sum via ones-MFMA
      lacc = __builtin_amdgcn_mfma_f32_16x16x32_bf16(pa0, ones, lacc, 0, 0, 0);
      lacc = __builtin_amdgcn_mfma_f32_16x16x32_bf16(pa1, ones, lacc, 0, 0, 0);
#pragma unroll
      for (int n = 0; n < 4; ++n) {
        s16x8 v0 = *(const s16x8*)&Vs[buf][(n * 16 + lm) * 64 + swz0];
        s16x8 v1 = *(const s16x8*)&Vs[buf][(n * 16 + lm) * 64 + swz1];
        oacc[n] =
            __builtin_amdgcn_mfma_f32_16x16x32_bf16(pa0, v0, oacc[n], 0, 0, 0);
        oacc[n] =
            __builtin_amdgcn_mfma_f32_16x16x32_bf16(pa1, v1, oacc[n], 0, 0, 0);
      }
      __builtin_amdgcn_s_barrier();  // all reads of buf done before overwrite
    }
    float inv[4];
#pragma unroll
    for (int r = 0; r < 4; ++r) inv[r] = 1.0f / lacc[r];
#pragma unroll
    for (int n = 0; n < 4; ++n)
#pragma unroll
      for (int r = 0; r < 4; ++r)
        o[obase + (size_t)(qw + lg * 4 + r) * C + n * 16 + lm] =
            f2bf(oacc[n][r] * inv[r]);
  }
}

// ---------- LayerNorm v2: single-pass (sum, sumsq) fused reduction ----------
// var = E[x^2] - mean^2 (no cancellation risk: x ~ N(0,1), mean^2 << E[x^2]).
// One paired blockReduce (2 barriers) instead of two sequential (4 barriers).
__global__ __launch_bounds__(256) void k_ln(
    const float* __restrict__ in, const float* __restrict__ g,
    const float* __restrict__ bsh, float* __restrict__ xout,
    u16* __restrict__ xbout) {
  __shared__ float red2[8];
  int row = blockIdx.x;
  int tid = threadIdx.x;
  f32x4 v = ((const f32x4*)(in + (size_t)row * C))[tid];
  float s = 0.f, s2 = 0.f;
#pragma unroll
  for (int j = 0; j < 4; ++j) {
    s += v[j];
    s2 += v[j] * v[j];
  }
  int lane = tid & 63, w = tid >> 6;
#pragma unroll
  for (int m = 32; m >= 1; m >>= 1) {
    s += __shfl_xor(s, m, 64);
    s2 += __shfl_xor(s2, m, 64);
  }
  if (lane == 0) {
    red2[w * 2] = s;
    red2[w * 2 + 1] = s2;
  }
  __syncthreads();
  s = red2[0] + red2[2] + red2[4] + red2[6];
  s2 = red2[1] + red2[3] + red2[5] + red2[7];
  float mean = s * (1.0f / C);
  float var = s2 * (1.0f / C) - mean * mean;
  float rstd = rsqrtf(var + 1e-5f);
  f32x4 gv = ((const f32x4*)g)[tid];
  f32x4 bv = ((const f32x4*)bsh)[tid];
  f32x4 y;
  s16x4 yb;
#pragma unroll
  for (int j = 0; j < 4; ++j) {
    y[j] = (v[j] - mean) * rstd * gv[j] + bv[j];
    yb[j] = (short)f2bf(y[j]);
  }
  ((f32x4*)(xout + (size_t)row * C))[tid] = y;
  ((s16x4*)(xbout + (size_t)row * C))[tid] = yb;
}

// ---------- loss: merge per-block exp-sums + target logit ----------
__global__ __launch_bounds__(128) void k_rowloss2(
    const float* __restrict__ sums, const float* __restrict__ logits,
    const int* __restrict__ tgt, float* __restrict__ rowloss) {
  int row = blockIdx.x;
  int tid = threadIdx.x;
  float s = (tid < 125) ? sums[(size_t)tid * BT + row] : 0.f;
#pragma unroll
  for (int d = 1; d < 64; d <<= 1) s += __shfl_xor(s, d, 64);
  __shared__ float ss[2];
  if ((tid & 63) == 0) ss[tid >> 6] = s;
  __syncthreads();
  if (tid == 0)
    rowloss[row] = logf(ss[0] + ss[1]) - logits[(size_t)row * V + tgt[row]];
}

__global__ __launch_bounds__(256) void k_lossreduce(
    const float* __restrict__ rowloss, float* __restrict__ out) {
  __shared__ float red[256];
  int tid = threadIdx.x;
  float s = 0.f;
  for (int i = tid; i < BT; i += 256) s += rowloss[i];
  red[tid] = s;
  __syncthreads();
  for (int m = 128; m >= 1; m >>= 1) {
    if (tid < m) red[tid] += red[tid + m];
    __syncthreads();
  }
  if (tid == 0) out[0] = red[0] * (1.0f / BT);
}

// ---------------- host orchestration ----------------
extern "C" void kernel_launch(void* const* d_in, const int* in_sizes, int n_in,
                              void* d_out, int out_size, void* d_ws,
                              size_t ws_size, hipStream_t stream) {
  (void)in_sizes; (void)n_in; (void)out_size; (void)ws_size;
  const int* index = (const int*)d_in[0];
  const int* targets = (const int*)d_in[1];
  const float* tok_emb = (const float*)d_in[2];
  const float* pos_emb = (const float*)d_in[3];
  const float* wq = (const float*)d_in[4];
  const float* wk = (const float*)d_in[5];
  const float* wv = (const float*)d_in[6];
  const float* wo = (const float*)d_in[7];
  const float* bo = (const float*)d_in[8];
  const float* w1 = (const float*)d_in[9];
  const float* b1 = (const float*)d_in[10];
  const float* w2 = (const float*)d_in[11];
  const float* b2 = (const float*)d_in[12];
  const float* ln1_g = (const float*)d_in[13];
  const float* ln1_b = (const float*)d_in[14];
  const float* ln2_g = (const float*)d_in[15];
  const float* ln2_b = (const float*)d_in[16];
  const float* lnf_g = (const float*)d_in[17];
  const float* lnf_b = (const float*)d_in[18];
  const float* lm_w = (const float*)d_in[19];
  const float* lm_b = (const float*)d_in[20];

  float* logits = (float*)d_out;
  float* loss = logits + (size_t)BT * V;

  size_t off = 0;
  auto alloc = [&](size_t bytes) -> void* {
    off = (off + 255) & ~(size_t)255;
    void* p = (void*)((char*)d_ws + off);
    off += bytes;
    return p;
  };
  u16* wqkv_t = (u16*)alloc((size_t)L * C3 * C * 2);  // [L][3C][C]
  u16* wo_t = (u16*)alloc((size_t)L * C * C * 2);
  u16* w1_t = (u16*)alloc((size_t)L * C * C4 * 2);
  u16* w2_t = (u16*)alloc((size_t)L * C4 * C * 2);
  u16* lmw_t = (u16*)alloc((size_t)V * C * 2);
  float* x = (float*)alloc((size_t)BT * C * 4);
  float* tmp = (float*)alloc((size_t)BT * C * 4);
  u16* xb = (u16*)alloc((size_t)BT * C * 2);
  u16* qkvb = (u16*)alloc((size_t)BT * C3 * 2);
  u16* vtb = (u16*)alloc((size_t)BT * C * 2);   // V transposed per (b,h)
  u16* attb = (u16*)alloc((size_t)BT * C * 2);
  u16* hb = (u16*)alloc((size_t)BT * C4 * 2);
  float* rowloss = (float*)alloc((size_t)BT * 4);
  float* sums = (float*)alloc((size_t)BT * 128 * 4);

  dim3 blk(256);
  dim3 blk5(512);
  k_transpose<<<dim3(C / 64, C / 64, L), blk, 0, stream>>>(
      wq, wqkv_t, C, C, (size_t)C * C, (size_t)C3 * C);
  k_transpose<<<dim3(C / 64, C / 64, L), blk, 0, stream>>>(
      wk, wqkv_t + (size_t)C * C, C, C, (size_t)C * C, (size_t)C3 * C);
  k_transpose<<<dim3(C / 64, C / 64, L), blk, 0, stream>>>(
      wv, wqkv_t + (size_t)2 * C * C, C, C, (size_t)C * C, (size_t)C3 * C);
  k_transpose<<<dim3(C / 64, C / 64, L), blk, 0, stream>>>(
      wo, wo_t, C, C, (size_t)C * C, (size_t)C * C);
  k_transpose<<<dim3(C4 / 64, C / 64, L), blk, 0, stream>>>(
      w1, w1_t, C, C4, (size_t)C * C4, (size_t)C * C4);
  k_transpose<<<dim3(C / 64, C4 / 64, L), blk, 0, stream>>>(
      w2, w2_t, C4, C, (size_t)C4 * C, (size_t)C4 * C);
  k_transpose<<<dim3(V / 64, C / 64, 1), blk, 0, stream>>>(
      lm_w, lmw_t, C, V, 0, 0);

  k_embed<<<BT, blk, 0, stream>>>(index, tok_emb, pos_emb, x, xb);

  dim3 gQKV(C3 / 128, BT / 128);   // 768 wg (128^2 ring, VT)
  dim3 gCC(C / 128, BT / 128);     // 256 wg (128^2 ring)
  dim3 gC4(C4 / 256, BT / 256);    // 256 wg (256^2 8-phase)
  for (int l = 0; l < L; ++l) {
    const u16* wqkvt = wqkv_t + (size_t)l * C3 * C;
    const u16* wot = wo_t + (size_t)l * C * C;
    const u16* w1t = w1_t + (size_t)l * C * C4;
    const u16* w2t = w2_t + (size_t)l * C4 * C;

    k_gemm<1, 0, 0, 0, 1><<<gQKV, blk, 0, stream>>>(
        xb, wqkvt, nullptr, nullptr, nullptr, qkvb, vtb, BT, C3, C);
    k_attn<<<B * H * 8, blk, 0, stream>>>(qkvb, vtb, attb);
    k_gemm<0, 0, 1, 1, 0><<<gCC, blk, 0, stream>>>(
        attb, wot, bo + (size_t)l * C, x, tmp, nullptr, nullptr, BT, C, C);
    k_ln<<<BT, blk, 0, stream>>>(tmp, ln1_g + (size_t)l * C,
                                 ln1_b + (size_t)l * C, x, xb);
    k_gemm256<1, 1, 1, 0><<<gC4, blk5, 0, stream>>>(
        xb, w1t, b1 + (size_t)l * C4, nullptr, nullptr, hb, BT, C4, C);
    k_gemm<0, 0, 1, 1, 0><<<gCC, blk, 0, stream>>>(
        hb, w2t, b2 + (size_t)l * C, x, tmp, nullptr, nullptr, BT, C, C4);
    k_ln<<<BT, blk, 0, stream>>>(tmp, ln2_g + (size_t)l * C,
                                 ln2_b + (size_t)l * C, x, xb);
  }
  k_ln<<<BT, blk, 0, stream>>>(x, lnf_g, lnf_b, x, xb);
  k_lmhead<<<dim3(V / 256, BT / 256), dim3(1024), 0, stream>>>(
      xb, lmw_t, lm_b, logits, sums, BT, V, C);
  k_rowloss2<<<BT, dim3(128), 0, stream>>>(sums, logits, targets, rowloss);
  k_lossreduce<<<1, blk, 0, stream>>>(rowloss, loss);
}